// Round 3
// baseline (241.843 us; speedup 1.0000x reference)
//
#include <hip/hip_runtime.h>
#include <math.h>

#define NSIG 1000
#define NP   3997      // interp points = FFT length (odd)
#define KHALF 1999     // distinct spectrum bins: k = 0..1998 (rest mirror)
#define NW   995       // n_windows
#define WIN  20
#define STEPW 4
#define BATCH 4

// ws layout (bytes):
//   ks   : BATCH*NP floats        @ 0       (63952)
//   tw   : NP float2              @ 64000   (31976)
//   S    : BATCH*NP float2        @ 96000   (only first KHALF/row used)
//   rmax : BATCH uint             @ 224000

__device__ __forceinline__ double interp_at(const float* __restrict__ s, int p) {
    int i0 = p >> 2;
    int si = p & 3;
    double ss = 0.25 * (double)si;
    const double A = -0.75;
    double d0 = ss + 1.0;
    double w0 = ((A * d0 - 5.0 * A) * d0 + 8.0 * A) * d0 - 4.0 * A;
    double w1 = ((A + 2.0) * ss - (A + 3.0)) * ss * ss + 1.0;
    double d2 = 1.0 - ss;
    double w2 = ((A + 2.0) * d2 - (A + 3.0)) * d2 * d2 + 1.0;
    double d3 = 2.0 - ss;
    double w3 = ((A * d3 - 5.0 * A) * d3 + 8.0 * A) * d3 - 4.0 * A;
    int im1 = i0 - 1; if (im1 < 0) im1 = 0;
    int ip1 = i0 + 1; if (ip1 > NSIG - 1) ip1 = NSIG - 1;
    int ip2 = i0 + 2; if (ip2 > NSIG - 1) ip2 = NSIG - 1;
    return w0 * (double)s[im1] + w1 * (double)s[i0] +
           w2 * (double)s[ip1] + w3 * (double)s[ip2];
}

// K1 (merged): blocks 0..15 build twiddle table (+ block 0 zeroes rmax);
// blocks 16..19 do interp -> row min -> kernel mix -> ks for b = bx-16.
__global__ __launch_bounds__(256) void init_kernel(
        const float* __restrict__ sig, const float* __restrict__ gamma_raw,
        float* __restrict__ ks, float2* __restrict__ tw,
        unsigned int* __restrict__ rmax) {
    int bx = blockIdx.x;
    int tid = threadIdx.x;
    if (bx < 16) {
        int m = bx * 256 + tid;
        if (m < NP) {
            double ang = -6.283185307179586476925286766559 * ((double)m / (double)NP);
            double sv, cv; sincos(ang, &sv, &cv);
            tw[m] = make_float2((float)cv, (float)sv);
        }
        if (bx == 0 && tid < BATCH) rmax[tid] = 0u;
        return;
    }
    __shared__ double red[256];
    int b = bx - 16;
    const float* srow = sig + b * NSIG;
    double lmin = 1e300;
    for (int p = tid; p < NP; p += 256)
        lmin = fmin(lmin, interp_at(srow, p));
    red[tid] = lmin;
    __syncthreads();
    for (int s = 128; s > 0; s >>= 1) {
        if (tid < s) red[tid] = fmin(red[tid], red[tid + s]);
        __syncthreads();
    }
    double m = fmin(red[0], 0.0);
    double g0r = (double)gamma_raw[0], g1r = (double)gamma_raw[1];
    double mx = fmax(g0r, g1r);
    double e0 = exp(g0r - mx), e1 = exp(g1r - mx);
    double inv = 1.0 / (e0 + e1);
    double g0 = e0 * inv, g1 = e1 * inv;
    for (int p = tid; p < NP; p += 256) {
        double x = interp_at(srow, p) - m;
        double poly = (x + 1.3) * (x + 1.3);
        double gauss = exp(-0.5 * (x - 0.7) * (x - 0.7));
        ks[b * NP + p] = (float)(g0 * poly + g1 * gauss);
    }
}

// K2: full DFT, half spectrum. Grid (250, BATCH), 256 thr = 8 k x 32 t-chunks.
// Double-precision phase recurrence.
__global__ __launch_bounds__(256) void dft_kernel(const float* __restrict__ ks,
                                                  float2* __restrict__ S) {
    __shared__ float  lks[NP];
    __shared__ double2 red[256];
    int b = blockIdx.y;
    int tid = threadIdx.x;
    int kk = tid & 7;
    int tc = tid >> 3;
    int k = blockIdx.x * 8 + kk;
    for (int i = tid; i < NP; i += 256) lks[i] = ks[b * NP + i];
    __syncthreads();

    double sr = 0.0, si = 0.0;
    if (k < KHALF) {
        int t0 = tc * 125;
        int t1 = t0 + 125; if (t1 > NP) t1 = NP;
        const double TWO_PI = 6.283185307179586476925286766559;
        double base = -TWO_PI / (double)NP;
        double rr, ri;
        sincos(base * (double)k, &ri, &rr);
        int m0 = (k * t0) % NP;
        double pr, pi;
        sincos(base * (double)m0, &pi, &pr);
        for (int t = t0; t < t1; ++t) {
            double kv = (double)lks[t];
            sr = fma(kv, pr, sr);
            si = fma(kv, pi, si);
            double nr = pr * rr - pi * ri;
            double ni = pr * ri + pi * rr;
            pr = nr; pi = ni;
        }
    }
    red[tid] = make_double2(sr, si);
    __syncthreads();
    for (int s = 128; s >= 8; s >>= 1) {
        if (tid < s) {
            red[tid].x += red[tid + s].x;
            red[tid].y += red[tid + s].y;
        }
        __syncthreads();
    }
    if (tid < 8) {
        int kw = blockIdx.x * 8 + tid;
        if (kw < KHALF)
            S[b * NP + kw] = make_float2((float)red[tid].x, (float)red[tid].y);
    }
}

// K3: per (b,w): Horner 20-tap DFT per bin, M=|D|, W=P*D, M1=|S-W|,
// alpha mask, result (mirrored write), row max via shuffles.
__global__ __launch_bounds__(256) void window_kernel(
        const float* __restrict__ ks, const float2* __restrict__ tw,
        const float2* __restrict__ S, const float* __restrict__ alpha_p,
        float* __restrict__ out, unsigned int* __restrict__ rmax) {
    __shared__ float ksw[WIN];
    __shared__ float red4[4];
    int b = blockIdx.y;
    int w = blockIdx.x;
    int start = w * STEPW;
    int tid = threadIdx.x;
    if (tid < WIN) ksw[tid] = ks[b * NP + start + tid];
    float alpha = *alpha_p;
    __syncthreads();

    // hoist taps into registers (broadcast LDS reads, once)
    float kw[WIN];
    #pragma unroll
    for (int j = 0; j < WIN; ++j) kw[j] = ksw[j];

    float Mv[8], M1v[8];
    float lmax = 0.f;
    #pragma unroll
    for (int c = 0; c < 8; ++c) {
        int k = tid + c * 256;
        float Mc = 0.f, M1c = 0.f;
        if (k < KHALF) {
            float2 r = tw[k];                 // coalesced, L2-resident
            // Horner: D = sum_j kw[j] * r^j
            float Dx = kw[WIN - 1], Dy = 0.f;
            #pragma unroll
            for (int j = WIN - 2; j >= 0; --j) {
                float nx = fmaf(Dx, r.x, fmaf(-Dy, r.y, kw[j]));
                float ny = fmaf(Dy, r.x, Dx * r.y);
                Dx = nx; Dy = ny;
            }
            Mc = sqrtf(Dx * Dx + Dy * Dy);    // |P|=1 => M=|D|
            float2 P = tw[(k * start) % NP];  // scattered, L2-resident
            float Wr = fmaf(P.x, Dx, -P.y * Dy);
            float Wi = fmaf(P.x, Dy,  P.y * Dx);
            float2 Sv = S[b * NP + k];
            float dr = Sv.x - Wr, di = Sv.y - Wi;
            M1c = sqrtf(dr * dr + di * di);
            lmax = fmaxf(lmax, Mc);
        }
        Mv[c] = Mc; M1v[c] = M1c;
    }
    // block max over M: wave shuffle reduce, then 4-wave combine
    #pragma unroll
    for (int off = 32; off > 0; off >>= 1)
        lmax = fmaxf(lmax, __shfl_xor(lmax, off));
    if ((tid & 63) == 0) red4[tid >> 6] = lmax;
    __syncthreads();
    float cutoff = fmaxf(fmaxf(red4[0], red4[1]), fmaxf(red4[2], red4[3])) * alpha;

    float rlmax = 0.f;
    size_t base = ((size_t)(b * NW + w)) * NP;
    #pragma unroll
    for (int c = 0; c < 8; ++c) {
        int k = tid + c * 256;
        if (k < KHALF) {
            float M = Mv[c];
            float res = 0.f;
            if (M > cutoff) res = fminf(M, M1v[c] * M);  // strong=1 path; else 0
            out[base + k] = res;
            if (k > 0) out[base + NP - k] = res;         // Hermitian mirror
            rlmax = fmaxf(rlmax, res);
        }
    }
    #pragma unroll
    for (int off = 32; off > 0; off >>= 1)
        rlmax = fmaxf(rlmax, __shfl_xor(rlmax, off));
    if ((tid & 63) == 0) atomicMax(&rmax[b], __float_as_uint(rlmax));
}

// K4: final threshold result * (result > beta*max); read half, write mirrored
__global__ void thresh_kernel(float* __restrict__ out,
                              const unsigned int* __restrict__ rmax,
                              const float* __restrict__ beta_p) {
    int b = blockIdx.z;
    int w = blockIdx.y;
    int k = blockIdx.x * 256 + threadIdx.x;
    if (k < KHALF) {
        float thr = (*beta_p) * __uint_as_float(rmax[b]);
        size_t base = ((size_t)(b * NW + w)) * NP;
        float v = out[base + k];
        if (v != 0.0f && !(v > thr)) {
            out[base + k] = 0.f;
            if (k > 0) out[base + NP - k] = 0.f;
        }
    }
}

extern "C" void kernel_launch(void* const* d_in, const int* in_sizes, int n_in,
                              void* d_out, int out_size, void* d_ws, size_t ws_size,
                              hipStream_t stream) {
    const float* sig       = (const float*)d_in[0];
    const float* alpha_p   = (const float*)d_in[1];
    const float* beta_p    = (const float*)d_in[2];
    const float* gamma_raw = (const float*)d_in[3];
    char* ws = (char*)d_ws;
    float*        ks   = (float*)(ws + 0);
    float2*       tw   = (float2*)(ws + 64000);
    float2*       S    = (float2*)(ws + 96000);
    unsigned int* rmax = (unsigned int*)(ws + 224000);
    float* out = (float*)d_out;

    hipLaunchKernelGGL(init_kernel,   dim3(20),         dim3(256), 0, stream, sig, gamma_raw, ks, tw, rmax);
    hipLaunchKernelGGL(dft_kernel,    dim3(250, BATCH), dim3(256), 0, stream, ks, S);
    hipLaunchKernelGGL(window_kernel, dim3(NW, BATCH),  dim3(256), 0, stream, ks, tw, S, alpha_p, out, rmax);
    hipLaunchKernelGGL(thresh_kernel, dim3(8, NW, BATCH), dim3(256), 0, stream, out, rmax, beta_p);
}

// Round 4
// 103.442 us; speedup vs baseline: 2.3380x; 2.3380x over previous
//
#include <hip/hip_runtime.h>
#include <math.h>

#define NSIG 1000
#define NP   3997      // interp points = FFT length (odd)
#define KHALF 1999     // distinct spectrum bins: k = 0..1998 (rest mirror)
#define NW   995       // n_windows
#define WIN  20
#define STEPW 4
#define BATCH 4

// ws layout (bytes):
//   ks   : BATCH*NP floats        @ 0       (63952)
//   tw   : NP float2              @ 64000   (31976)
//   S    : BATCH*NP float2        @ 96000   (only first KHALF/row used)
//   rmax : BATCH uint             @ 224000

__device__ __forceinline__ double interp_at(const float* __restrict__ s, int p) {
    int i0 = p >> 2;
    int si = p & 3;
    double ss = 0.25 * (double)si;
    const double A = -0.75;
    double d0 = ss + 1.0;
    double w0 = ((A * d0 - 5.0 * A) * d0 + 8.0 * A) * d0 - 4.0 * A;
    double w1 = ((A + 2.0) * ss - (A + 3.0)) * ss * ss + 1.0;
    double d2 = 1.0 - ss;
    double w2 = ((A + 2.0) * d2 - (A + 3.0)) * d2 * d2 + 1.0;
    double d3 = 2.0 - ss;
    double w3 = ((A * d3 - 5.0 * A) * d3 + 8.0 * A) * d3 - 4.0 * A;
    int im1 = i0 - 1; if (im1 < 0) im1 = 0;
    int ip1 = i0 + 1; if (ip1 > NSIG - 1) ip1 = NSIG - 1;
    int ip2 = i0 + 2; if (ip2 > NSIG - 1) ip2 = NSIG - 1;
    return w0 * (double)s[im1] + w1 * (double)s[i0] +
           w2 * (double)s[ip1] + w3 * (double)s[ip2];
}

// K1 (merged): blocks 0..15 build twiddle table (+ block 0 zeroes rmax);
// blocks 16..19 do interp -> row min -> kernel mix -> ks for b = bx-16.
__global__ __launch_bounds__(256) void init_kernel(
        const float* __restrict__ sig, const float* __restrict__ gamma_raw,
        float* __restrict__ ks, float2* __restrict__ tw,
        unsigned int* __restrict__ rmax) {
    int bx = blockIdx.x;
    int tid = threadIdx.x;
    if (bx < 16) {
        int m = bx * 256 + tid;
        if (m < NP) {
            double ang = -6.283185307179586476925286766559 * ((double)m / (double)NP);
            double sv, cv; sincos(ang, &sv, &cv);
            tw[m] = make_float2((float)cv, (float)sv);
        }
        if (bx == 0 && tid < BATCH) rmax[tid] = 0u;
        return;
    }
    __shared__ double red[256];
    int b = bx - 16;
    const float* srow = sig + b * NSIG;
    double lmin = 1e300;
    for (int p = tid; p < NP; p += 256)
        lmin = fmin(lmin, interp_at(srow, p));
    red[tid] = lmin;
    __syncthreads();
    for (int s = 128; s > 0; s >>= 1) {
        if (tid < s) red[tid] = fmin(red[tid], red[tid + s]);
        __syncthreads();
    }
    double m = fmin(red[0], 0.0);
    double g0r = (double)gamma_raw[0], g1r = (double)gamma_raw[1];
    double mx = fmax(g0r, g1r);
    double e0 = exp(g0r - mx), e1 = exp(g1r - mx);
    double inv = 1.0 / (e0 + e1);
    double g0 = e0 * inv, g1 = e1 * inv;
    for (int p = tid; p < NP; p += 256) {
        double x = interp_at(srow, p) - m;
        double poly = (x + 1.3) * (x + 1.3);
        double gauss = exp(-0.5 * (x - 0.7) * (x - 0.7));
        ks[b * NP + p] = (float)(g0 * poly + g1 * gauss);
    }
}

// K2: full DFT, half spectrum. Grid (250, BATCH), 256 thr = 8 k x 32 t-chunks.
// Double-precision phase recurrence.
__global__ __launch_bounds__(256) void dft_kernel(const float* __restrict__ ks,
                                                  float2* __restrict__ S) {
    __shared__ float  lks[NP];
    __shared__ double2 red[256];
    int b = blockIdx.y;
    int tid = threadIdx.x;
    int kk = tid & 7;
    int tc = tid >> 3;
    int k = blockIdx.x * 8 + kk;
    for (int i = tid; i < NP; i += 256) lks[i] = ks[b * NP + i];
    __syncthreads();

    double sr = 0.0, si = 0.0;
    if (k < KHALF) {
        int t0 = tc * 125;
        int t1 = t0 + 125; if (t1 > NP) t1 = NP;
        const double TWO_PI = 6.283185307179586476925286766559;
        double base = -TWO_PI / (double)NP;
        double rr, ri;
        sincos(base * (double)k, &ri, &rr);
        int m0 = (k * t0) % NP;
        double pr, pi;
        sincos(base * (double)m0, &pi, &pr);
        for (int t = t0; t < t1; ++t) {
            double kv = (double)lks[t];
            sr = fma(kv, pr, sr);
            si = fma(kv, pi, si);
            double nr = pr * rr - pi * ri;
            double ni = pr * ri + pi * rr;
            pr = nr; pi = ni;
        }
    }
    red[tid] = make_double2(sr, si);
    __syncthreads();
    for (int s = 128; s >= 8; s >>= 1) {
        if (tid < s) {
            red[tid].x += red[tid + s].x;
            red[tid].y += red[tid + s].y;
        }
        __syncthreads();
    }
    if (tid < 8) {
        int kw = blockIdx.x * 8 + tid;
        if (kw < KHALF)
            S[b * NP + kw] = make_float2((float)red[tid].x, (float)red[tid].y);
    }
}

// K3: per (b,w): Horner 20-tap DFT, 2 bins/thread with NAMED scalars
// (no runtime-indexed arrays -> no scratch). 1024 threads.
__global__ __launch_bounds__(1024) void window_kernel(
        const float* __restrict__ ks, const float2* __restrict__ tw,
        const float2* __restrict__ S, const float* __restrict__ alpha_p,
        float* __restrict__ out, unsigned int* __restrict__ rmax) {
    __shared__ float ksw[WIN];
    __shared__ float wred[16];
    int b = blockIdx.y;
    int w = blockIdx.x;
    int start = w * STEPW;
    int tid = threadIdx.x;
    if (tid < WIN) ksw[tid] = ks[b * NP + start + tid];
    float alpha = *alpha_p;
    __syncthreads();

    float kw[WIN];
    #pragma unroll
    for (int j = 0; j < WIN; ++j) kw[j] = ksw[j];

    int k0 = tid;            // always < KHALF (1024 <= 1999)
    int k1 = tid + 1024;     // valid iff < KHALF
    bool v1 = (k1 < KHALF);

    // ---- bin 0 ----
    float2 r0 = tw[k0];
    float D0x = kw[WIN - 1], D0y = 0.f;
    #pragma unroll
    for (int j = WIN - 2; j >= 0; --j) {
        float nx = fmaf(D0x, r0.x, fmaf(-D0y, r0.y, kw[j]));
        float ny = fmaf(D0y, r0.x, D0x * r0.y);
        D0x = nx; D0y = ny;
    }
    float Ma = sqrtf(D0x * D0x + D0y * D0y);
    float2 P0 = tw[(k0 * start) % NP];
    float W0r = fmaf(P0.x, D0x, -P0.y * D0y);
    float W0i = fmaf(P0.x, D0y,  P0.y * D0x);
    float2 Sv0 = S[b * NP + k0];
    float d0r = Sv0.x - W0r, d0i = Sv0.y - W0i;
    float M1a = sqrtf(d0r * d0r + d0i * d0i);

    // ---- bin 1 ----
    float Mb = 0.f, M1b = 0.f;
    if (v1) {
        float2 r1 = tw[k1];
        float D1x = kw[WIN - 1], D1y = 0.f;
        #pragma unroll
        for (int j = WIN - 2; j >= 0; --j) {
            float nx = fmaf(D1x, r1.x, fmaf(-D1y, r1.y, kw[j]));
            float ny = fmaf(D1y, r1.x, D1x * r1.y);
            D1x = nx; D1y = ny;
        }
        Mb = sqrtf(D1x * D1x + D1y * D1y);
        float2 P1 = tw[(k1 * start) % NP];
        float W1r = fmaf(P1.x, D1x, -P1.y * D1y);
        float W1i = fmaf(P1.x, D1y,  P1.y * D1x);
        float2 Sv1 = S[b * NP + k1];
        float d1r = Sv1.x - W1r, d1i = Sv1.y - W1i;
        M1b = sqrtf(d1r * d1r + d1i * d1i);
    }

    // block max of M: wave shuffle + LDS combine
    float lmax = fmaxf(Ma, Mb);
    #pragma unroll
    for (int off = 32; off > 0; off >>= 1)
        lmax = fmaxf(lmax, __shfl_xor(lmax, off));
    if ((tid & 63) == 0) wred[tid >> 6] = lmax;
    __syncthreads();
    float bmax = wred[0];
    #pragma unroll
    for (int i = 1; i < 16; ++i) bmax = fmaxf(bmax, wred[i]);
    float cutoff = bmax * alpha;

    size_t base = ((size_t)(b * NW + w)) * NP;
    float res0 = 0.f;
    if (Ma > cutoff) res0 = fminf(Ma, M1a * Ma);
    out[base + k0] = res0;
    if (k0 > 0) out[base + NP - k0] = res0;
    float res1 = 0.f;
    if (v1) {
        if (Mb > cutoff) res1 = fminf(Mb, M1b * Mb);
        out[base + k1] = res1;
        out[base + NP - k1] = res1;
    }

    // block max of result -> one atomic per block
    float rlmax = fmaxf(res0, res1);
    #pragma unroll
    for (int off = 32; off > 0; off >>= 1)
        rlmax = fmaxf(rlmax, __shfl_xor(rlmax, off));
    if ((tid & 63) == 0) wred[tid >> 6] = rlmax;
    __syncthreads();
    if (tid == 0) {
        float bm = wred[0];
        #pragma unroll
        for (int i = 1; i < 16; ++i) bm = fmaxf(bm, wred[i]);
        atomicMax(&rmax[b], __float_as_uint(bm));
    }
}

// K4: final threshold result * (result > beta*max); read half, write mirrored
__global__ void thresh_kernel(float* __restrict__ out,
                              const unsigned int* __restrict__ rmax,
                              const float* __restrict__ beta_p) {
    int b = blockIdx.z;
    int w = blockIdx.y;
    int k = blockIdx.x * 256 + threadIdx.x;
    if (k < KHALF) {
        float thr = (*beta_p) * __uint_as_float(rmax[b]);
        size_t base = ((size_t)(b * NW + w)) * NP;
        float v = out[base + k];
        if (v != 0.0f && !(v > thr)) {
            out[base + k] = 0.f;
            if (k > 0) out[base + NP - k] = 0.f;
        }
    }
}

extern "C" void kernel_launch(void* const* d_in, const int* in_sizes, int n_in,
                              void* d_out, int out_size, void* d_ws, size_t ws_size,
                              hipStream_t stream) {
    const float* sig       = (const float*)d_in[0];
    const float* alpha_p   = (const float*)d_in[1];
    const float* beta_p    = (const float*)d_in[2];
    const float* gamma_raw = (const float*)d_in[3];
    char* ws = (char*)d_ws;
    float*        ks   = (float*)(ws + 0);
    float2*       tw   = (float2*)(ws + 64000);
    float2*       S    = (float2*)(ws + 96000);
    unsigned int* rmax = (unsigned int*)(ws + 224000);
    float* out = (float*)d_out;

    hipLaunchKernelGGL(init_kernel,   dim3(20),         dim3(256),  0, stream, sig, gamma_raw, ks, tw, rmax);
    hipLaunchKernelGGL(dft_kernel,    dim3(250, BATCH), dim3(256),  0, stream, ks, S);
    hipLaunchKernelGGL(window_kernel, dim3(NW, BATCH),  dim3(1024), 0, stream, ks, tw, S, alpha_p, out, rmax);
    hipLaunchKernelGGL(thresh_kernel, dim3(8, NW, BATCH), dim3(256), 0, stream, out, rmax, beta_p);
}

// Round 5
// 82.628 us; speedup vs baseline: 2.9269x; 1.2519x over previous
//
#include <hip/hip_runtime.h>
#include <math.h>

#define NSIG 1000
#define NP   3997      // interp points = FFT length (odd)
#define KHALF 1999     // distinct spectrum bins: k = 0..1998 (rest mirror)
#define NW   995       // n_windows
#define WIN  20
#define STEPW 4
#define BATCH 4

// ws layout (bytes):
//   ks   : BATCH*NP floats        @ 0       (63952)
//   tw   : NP float2              @ 64000   (31976)
//   S    : BATCH*NP float2        @ 96000   (only first KHALF/row used)
//   rmax : BATCH uint             @ 224000

__device__ __forceinline__ double interp_at(const float* __restrict__ s, int p) {
    int i0 = p >> 2;
    int si = p & 3;
    double ss = 0.25 * (double)si;
    const double A = -0.75;
    double d0 = ss + 1.0;
    double w0 = ((A * d0 - 5.0 * A) * d0 + 8.0 * A) * d0 - 4.0 * A;
    double w1 = ((A + 2.0) * ss - (A + 3.0)) * ss * ss + 1.0;
    double d2 = 1.0 - ss;
    double w2 = ((A + 2.0) * d2 - (A + 3.0)) * d2 * d2 + 1.0;
    double d3 = 2.0 - ss;
    double w3 = ((A * d3 - 5.0 * A) * d3 + 8.0 * A) * d3 - 4.0 * A;
    int im1 = i0 - 1; if (im1 < 0) im1 = 0;
    int ip1 = i0 + 1; if (ip1 > NSIG - 1) ip1 = NSIG - 1;
    int ip2 = i0 + 2; if (ip2 > NSIG - 1) ip2 = NSIG - 1;
    return w0 * (double)s[im1] + w1 * (double)s[i0] +
           w2 * (double)s[ip1] + w3 * (double)s[ip2];
}

// K1 (merged): blocks 0..15 build twiddle table (+ block 0 zeroes rmax);
// blocks 16..19 do interp -> row min -> kernel mix -> ks for b = bx-16.
__global__ __launch_bounds__(256) void init_kernel(
        const float* __restrict__ sig, const float* __restrict__ gamma_raw,
        float* __restrict__ ks, float2* __restrict__ tw,
        unsigned int* __restrict__ rmax) {
    int bx = blockIdx.x;
    int tid = threadIdx.x;
    if (bx < 16) {
        int m = bx * 256 + tid;
        if (m < NP) {
            double ang = -6.283185307179586476925286766559 * ((double)m / (double)NP);
            double sv, cv; sincos(ang, &sv, &cv);
            tw[m] = make_float2((float)cv, (float)sv);
        }
        if (bx == 0 && tid < BATCH) rmax[tid] = 0u;
        return;
    }
    __shared__ double red[256];
    int b = bx - 16;
    const float* srow = sig + b * NSIG;
    double lmin = 1e300;
    for (int p = tid; p < NP; p += 256)
        lmin = fmin(lmin, interp_at(srow, p));
    red[tid] = lmin;
    __syncthreads();
    for (int s = 128; s > 0; s >>= 1) {
        if (tid < s) red[tid] = fmin(red[tid], red[tid + s]);
        __syncthreads();
    }
    double m = fmin(red[0], 0.0);
    double g0r = (double)gamma_raw[0], g1r = (double)gamma_raw[1];
    double mx = fmax(g0r, g1r);
    double e0 = exp(g0r - mx), e1 = exp(g1r - mx);
    double inv = 1.0 / (e0 + e1);
    double g0 = e0 * inv, g1 = e1 * inv;
    for (int p = tid; p < NP; p += 256) {
        double x = interp_at(srow, p) - m;
        double poly = (x + 1.3) * (x + 1.3);
        double gauss = exp(-0.5 * (x - 0.7) * (x - 0.7));
        ks[b * NP + p] = (float)(g0 * poly + g1 * gauss);
    }
}

// K2: full DFT, half spectrum. Grid (250, BATCH), 256 thr = 8 k x 32 t-chunks.
// Double-precision phase recurrence.
__global__ __launch_bounds__(256) void dft_kernel(const float* __restrict__ ks,
                                                  float2* __restrict__ S) {
    __shared__ float  lks[NP];
    __shared__ double2 red[256];
    int b = blockIdx.y;
    int tid = threadIdx.x;
    int kk = tid & 7;
    int tc = tid >> 3;
    int k = blockIdx.x * 8 + kk;
    for (int i = tid; i < NP; i += 256) lks[i] = ks[b * NP + i];
    __syncthreads();

    double sr = 0.0, si = 0.0;
    if (k < KHALF) {
        int t0 = tc * 125;
        int t1 = t0 + 125; if (t1 > NP) t1 = NP;
        const double TWO_PI = 6.283185307179586476925286766559;
        double base = -TWO_PI / (double)NP;
        double rr, ri;
        sincos(base * (double)k, &ri, &rr);
        int m0 = (k * t0) % NP;
        double pr, pi;
        sincos(base * (double)m0, &pi, &pr);
        for (int t = t0; t < t1; ++t) {
            double kv = (double)lks[t];
            sr = fma(kv, pr, sr);
            si = fma(kv, pi, si);
            double nr = pr * rr - pi * ri;
            double ni = pr * ri + pi * rr;
            pr = nr; pi = ni;
        }
    }
    red[tid] = make_double2(sr, si);
    __syncthreads();
    for (int s = 128; s >= 8; s >>= 1) {
        if (tid < s) {
            red[tid].x += red[tid + s].x;
            red[tid].y += red[tid + s].y;
        }
        __syncthreads();
    }
    if (tid < 8) {
        int kw = blockIdx.x * 8 + tid;
        if (kw < KHALF)
            S[b * NP + kw] = make_float2((float)red[tid].x, (float)red[tid].y);
    }
}

// K3: 2 windows per block, 2 bins/thread, taps via uniform (SGPR) loads.
// Writes COMPACT res (k < KHALF only); mirror done by thresh_kernel.
__global__ __launch_bounds__(1024) void window_kernel(
        const float* __restrict__ ks, const float2* __restrict__ tw,
        const float2* __restrict__ S, const float* __restrict__ alpha_p,
        float* __restrict__ out, unsigned int* __restrict__ rmax) {
    __shared__ float wred[32];
    int b = blockIdx.y;
    int w0 = blockIdx.x * 2;
    int w1 = w0 + 1;
    bool haveW1 = (w1 < NW);
    int s0 = w0 * STEPW;                 // s1 = s0 + 4
    int tid = threadIdx.x;
    float alpha = *alpha_p;
    const float* kp = ks + b * NP + s0;  // uniform base -> s_load taps

    int k0 = tid;                        // < KHALF always
    int k1 = tid + 1024;
    bool v1 = (k1 < KHALF);
    int k1c = v1 ? k1 : 0;

    // issue all latency-bearing loads before the Horner chains
    float2 r0 = tw[k0];
    float2 r1 = tw[k1c];
    float2 Sv0 = S[b * NP + k0];
    float2 Sv1 = S[b * NP + k1c];
    int s1 = s0 + STEPW;
    float2 P00 = tw[(k0 * s0) % NP];     // win0 bin0 (k*s <= 1998*3980, fits i32)
    float2 P10 = tw[(k0 * s1) % NP];     // win1 bin0
    float2 P01 = tw[(k1c * s0) % NP];    // win0 bin1
    float2 P11 = tw[(k1c * s1) % NP];    // win1 bin1

    // 4 independent Horner chains: D[win][bin]
    float D00x = kp[19], D00y = 0.f;
    float D10x = kp[23], D10y = 0.f;
    float D01x = kp[19], D01y = 0.f;
    float D11x = kp[23], D11y = 0.f;
    #pragma unroll
    for (int j = 18; j >= 0; --j) {
        float a0 = kp[j], a1 = kp[j + 4];
        float nx, ny;
        nx = fmaf(D00x, r0.x, fmaf(-D00y, r0.y, a0));
        ny = fmaf(D00y, r0.x, D00x * r0.y);
        D00x = nx; D00y = ny;
        nx = fmaf(D10x, r0.x, fmaf(-D10y, r0.y, a1));
        ny = fmaf(D10y, r0.x, D10x * r0.y);
        D10x = nx; D10y = ny;
        nx = fmaf(D01x, r1.x, fmaf(-D01y, r1.y, a0));
        ny = fmaf(D01y, r1.x, D01x * r1.y);
        D01x = nx; D01y = ny;
        nx = fmaf(D11x, r1.x, fmaf(-D11y, r1.y, a1));
        ny = fmaf(D11y, r1.x, D11x * r1.y);
        D11x = nx; D11y = ny;
    }

    float M00 = sqrtf(D00x * D00x + D00y * D00y);
    float M10 = sqrtf(D10x * D10x + D10y * D10y);
    float M01 = v1 ? sqrtf(D01x * D01x + D01y * D01y) : 0.f;
    float M11 = v1 ? sqrtf(D11x * D11x + D11y * D11y) : 0.f;

    // block max of M per window
    float lm0 = fmaxf(M00, M01);
    float lm1 = fmaxf(M10, M11);
    #pragma unroll
    for (int off = 32; off > 0; off >>= 1) {
        lm0 = fmaxf(lm0, __shfl_xor(lm0, off));
        lm1 = fmaxf(lm1, __shfl_xor(lm1, off));
    }
    int wv = tid >> 6;
    if ((tid & 63) == 0) { wred[wv] = lm0; wred[16 + wv] = lm1; }
    __syncthreads();
    float bm0 = wred[0], bm1 = wred[16];
    #pragma unroll
    for (int i = 1; i < 16; ++i) {
        bm0 = fmaxf(bm0, wred[i]);
        bm1 = fmaxf(bm1, wred[16 + i]);
    }
    float cut0 = bm0 * alpha, cut1 = bm1 * alpha;

    // W = P*D, M1 = |S - W|, res = (M>cut) ? min(M, M1*M) : 0
    float res00 = 0.f, res10 = 0.f, res01 = 0.f, res11 = 0.f;
    {
        float Wr = fmaf(P00.x, D00x, -P00.y * D00y);
        float Wi = fmaf(P00.x, D00y,  P00.y * D00x);
        float dr = Sv0.x - Wr, di = Sv0.y - Wi;
        float M1 = sqrtf(dr * dr + di * di);
        if (M00 > cut0) res00 = fminf(M00, M1 * M00);
    }
    {
        float Wr = fmaf(P10.x, D10x, -P10.y * D10y);
        float Wi = fmaf(P10.x, D10y,  P10.y * D10x);
        float dr = Sv0.x - Wr, di = Sv0.y - Wi;
        float M1 = sqrtf(dr * dr + di * di);
        if (M10 > cut1) res10 = fminf(M10, M1 * M10);
    }
    if (v1) {
        {
            float Wr = fmaf(P01.x, D01x, -P01.y * D01y);
            float Wi = fmaf(P01.x, D01y,  P01.y * D01x);
            float dr = Sv1.x - Wr, di = Sv1.y - Wi;
            float M1 = sqrtf(dr * dr + di * di);
            if (M01 > cut0) res01 = fminf(M01, M1 * M01);
        }
        {
            float Wr = fmaf(P11.x, D11x, -P11.y * D11y);
            float Wi = fmaf(P11.x, D11y,  P11.y * D11x);
            float dr = Sv1.x - Wr, di = Sv1.y - Wi;
            float M1 = sqrtf(dr * dr + di * di);
            if (M11 > cut1) res11 = fminf(M11, M1 * M11);
        }
    }

    // compact writes (k < KHALF slots only)
    size_t base0 = ((size_t)(b * NW + w0)) * NP;
    out[base0 + k0] = res00;
    if (v1) out[base0 + k1] = res01;
    if (haveW1) {
        size_t base1 = base0 + NP;
        out[base1 + k0] = res10;
        if (v1) out[base1 + k1] = res11;
    }

    // block max of res -> one atomic (win1 ignored if invalid)
    float rl = fmaxf(fmaxf(res00, res01),
                     haveW1 ? fmaxf(res10, res11) : 0.f);
    #pragma unroll
    for (int off = 32; off > 0; off >>= 1)
        rl = fmaxf(rl, __shfl_xor(rl, off));
    __syncthreads();
    if ((tid & 63) == 0) wred[wv] = rl;
    __syncthreads();
    if (tid == 0) {
        float bm = wred[0];
        #pragma unroll
        for (int i = 1; i < 16; ++i) bm = fmaxf(bm, wred[i]);
        atomicMax(&rmax[b], __float_as_uint(bm));
    }
}

// K4: one block per (b,w) row: read compact res, threshold, write full
// mirrored row. Each slot k<KHALF is read and written by exactly one thread
// (k0=tid, k1=tid+1024), mirrors land in the write-only upper half -> no
// barrier needed.
__global__ __launch_bounds__(1024) void thresh_kernel(
        float* __restrict__ out, const unsigned int* __restrict__ rmax,
        const float* __restrict__ beta_p) {
    int b = blockIdx.y;
    int w = blockIdx.x;
    size_t base = ((size_t)(b * NW + w)) * NP;
    float thr = (*beta_p) * __uint_as_float(rmax[b]);
    int k0 = threadIdx.x;
    int k1 = k0 + 1024;
    float v0 = out[base + k0];
    float f0 = (v0 > thr) ? v0 : 0.f;
    out[base + k0] = f0;
    if (k0 > 0) out[base + NP - k0] = f0;
    if (k1 < KHALF) {
        float v1v = out[base + k1];
        float f1 = (v1v > thr) ? v1v : 0.f;
        out[base + k1] = f1;
        out[base + NP - k1] = f1;
    }
}

extern "C" void kernel_launch(void* const* d_in, const int* in_sizes, int n_in,
                              void* d_out, int out_size, void* d_ws, size_t ws_size,
                              hipStream_t stream) {
    const float* sig       = (const float*)d_in[0];
    const float* alpha_p   = (const float*)d_in[1];
    const float* beta_p    = (const float*)d_in[2];
    const float* gamma_raw = (const float*)d_in[3];
    char* ws = (char*)d_ws;
    float*        ks   = (float*)(ws + 0);
    float2*       tw   = (float2*)(ws + 64000);
    float2*       S    = (float2*)(ws + 96000);
    unsigned int* rmax = (unsigned int*)(ws + 224000);
    float* out = (float*)d_out;

    hipLaunchKernelGGL(init_kernel,   dim3(20),              dim3(256),  0, stream, sig, gamma_raw, ks, tw, rmax);
    hipLaunchKernelGGL(dft_kernel,    dim3(250, BATCH),      dim3(256),  0, stream, ks, S);
    hipLaunchKernelGGL(window_kernel, dim3((NW + 1) / 2, BATCH), dim3(1024), 0, stream, ks, tw, S, alpha_p, out, rmax);
    hipLaunchKernelGGL(thresh_kernel, dim3(NW, BATCH),       dim3(1024), 0, stream, out, rmax, beta_p);
}

// Round 6
// 73.387 us; speedup vs baseline: 3.2954x; 1.1259x over previous
//
#include <hip/hip_runtime.h>
#include <math.h>

#define NSIG 1000
#define NP   3997      // interp points = FFT length (odd)
#define KHALF 1999     // distinct spectrum bins: k = 0..1998 (rest mirror)
#define NW   995       // n_windows
#define WIN  20
#define STEPW 4
#define BATCH 4
#define NCH  125       // window chunks per batch row (8 windows each)
#define CW   8         // windows per chunk
#define RS   2000      // compact res row stride (floats)

// ws layout (bytes), ws ~= 256 MiB:
//   ks   : [0, 65536)        BATCH*NP floats + pad (pad stays poison; read-only garbage for tail windows)
//   tw   : [65536, 97512)    NP float2
//   S    : [98304, 226208)   BATCH*NP float2 (first KHALF per row used)
//   rmax : [226304, 226320)  BATCH uint
//   cmax : [226432, 228432)  BATCH*NCH floats
//   resc : [262144, ~32MB)   BATCH*NW rows of RS floats (compact res)

__device__ __forceinline__ double interp_at(const float* __restrict__ s, int p) {
    int i0 = p >> 2;
    int si = p & 3;
    double ss = 0.25 * (double)si;
    const double A = -0.75;
    double d0 = ss + 1.0;
    double w0 = ((A * d0 - 5.0 * A) * d0 + 8.0 * A) * d0 - 4.0 * A;
    double w1 = ((A + 2.0) * ss - (A + 3.0)) * ss * ss + 1.0;
    double d2 = 1.0 - ss;
    double w2 = ((A + 2.0) * d2 - (A + 3.0)) * d2 * d2 + 1.0;
    double d3 = 2.0 - ss;
    double w3 = ((A * d3 - 5.0 * A) * d3 + 8.0 * A) * d3 - 4.0 * A;
    int im1 = i0 - 1; if (im1 < 0) im1 = 0;
    int ip1 = i0 + 1; if (ip1 > NSIG - 1) ip1 = NSIG - 1;
    int ip2 = i0 + 2; if (ip2 > NSIG - 1) ip2 = NSIG - 1;
    return w0 * (double)s[im1] + w1 * (double)s[i0] +
           w2 * (double)s[ip1] + w3 * (double)s[ip2];
}

// K1: blocks 0..15 twiddle table (+ block 0 zeroes rmax); 16..19 build ks.
__global__ __launch_bounds__(256) void init_kernel(
        const float* __restrict__ sig, const float* __restrict__ gamma_raw,
        float* __restrict__ ks, float2* __restrict__ tw,
        unsigned int* __restrict__ rmax) {
    int bx = blockIdx.x;
    int tid = threadIdx.x;
    if (bx < 16) {
        int m = bx * 256 + tid;
        if (m < NP) {
            double ang = -6.283185307179586476925286766559 * ((double)m / (double)NP);
            double sv, cv; sincos(ang, &sv, &cv);
            tw[m] = make_float2((float)cv, (float)sv);
        }
        if (bx == 0 && tid < BATCH) rmax[tid] = 0u;
        return;
    }
    __shared__ double red[256];
    int b = bx - 16;
    const float* srow = sig + b * NSIG;
    double lmin = 1e300;
    for (int p = tid; p < NP; p += 256)
        lmin = fmin(lmin, interp_at(srow, p));
    red[tid] = lmin;
    __syncthreads();
    for (int s = 128; s > 0; s >>= 1) {
        if (tid < s) red[tid] = fmin(red[tid], red[tid + s]);
        __syncthreads();
    }
    double m = fmin(red[0], 0.0);
    double g0r = (double)gamma_raw[0], g1r = (double)gamma_raw[1];
    double mx = fmax(g0r, g1r);
    double e0 = exp(g0r - mx), e1 = exp(g1r - mx);
    double inv = 1.0 / (e0 + e1);
    double g0 = e0 * inv, g1 = e1 * inv;
    for (int p = tid; p < NP; p += 256) {
        double x = interp_at(srow, p) - m;
        double poly = (x + 1.3) * (x + 1.3);
        double gauss = exp(-0.5 * (x - 0.7) * (x - 0.7));
        ks[b * NP + p] = (float)(g0 * poly + g1 * gauss);
    }
}

// K2: full DFT, half spectrum, double-precision phase recurrence.
__global__ __launch_bounds__(256) void dft_kernel(const float* __restrict__ ks,
                                                  float2* __restrict__ S) {
    __shared__ float  lks[NP];
    __shared__ double2 red[256];
    int b = blockIdx.y;
    int tid = threadIdx.x;
    int kk = tid & 7;
    int tc = tid >> 3;
    int k = blockIdx.x * 8 + kk;
    for (int i = tid; i < NP; i += 256) lks[i] = ks[b * NP + i];
    __syncthreads();

    double sr = 0.0, si = 0.0;
    if (k < KHALF) {
        int t0 = tc * 125;
        int t1 = t0 + 125; if (t1 > NP) t1 = NP;
        const double TWO_PI = 6.283185307179586476925286766559;
        double base = -TWO_PI / (double)NP;
        double rr, ri;
        sincos(base * (double)k, &ri, &rr);
        int m0 = (k * t0) % NP;
        double pr, pi;
        sincos(base * (double)m0, &pi, &pr);
        for (int t = t0; t < t1; ++t) {
            double kv = (double)lks[t];
            sr = fma(kv, pr, sr);
            si = fma(kv, pi, si);
            double nr = pr * rr - pi * ri;
            double ni = pr * ri + pi * rr;
            pr = nr; pi = ni;
        }
    }
    red[tid] = make_double2(sr, si);
    __syncthreads();
    for (int s = 128; s >= 8; s >>= 1) {
        if (tid < s) {
            red[tid].x += red[tid + s].x;
            red[tid].y += red[tid + s].y;
        }
        __syncthreads();
    }
    if (tid < 8) {
        int kw = blockIdx.x * 8 + tid;
        if (kw < KHALF)
            S[b * NP + kw] = make_float2((float)red[tid].x, (float)red[tid].y);
    }
}

__device__ __forceinline__ float wavemax(float x) {
    #pragma unroll
    for (int off = 32; off > 0; off >>= 1)
        x = fmaxf(x, __shfl_xor(x, off));
    return x;
}

// one sliding step for bin n with old tap co leaving, new tap cn entering:
// W += (cn*r20 - co) * q ; q *= r
#define SLIDE1(n, co, cn) { \
    float ax = fmaf((cn), T##n.x, -(co)); \
    float ay = (cn) * T##n.y; \
    Wx##n = fmaf(ax, Q##n.x, fmaf(-ay, Q##n.y, Wx##n)); \
    Wy##n = fmaf(ax, Q##n.y, fmaf(ay, Q##n.x, Wy##n)); \
    float tq = fmaf(Q##n.x, R##n.x, -(Q##n.y * R##n.y)); \
    Q##n.y = fmaf(Q##n.x, R##n.y, Q##n.y * R##n.x); \
    Q##n.x = tq; }

#define SLIDEJ(co, cn) SLIDE1(0, co, cn) SLIDE1(1, co, cn) SLIDE1(2, co, cn) SLIDE1(3, co, cn)

#define SLIDE4(base) { \
    { float co = kp[(base) + 0], cn = kp[(base) + 20]; SLIDEJ(co, cn) } \
    { float co = kp[(base) + 1], cn = kp[(base) + 21]; SLIDEJ(co, cn) } \
    { float co = kp[(base) + 2], cn = kp[(base) + 22]; SLIDEJ(co, cn) } \
    { float co = kp[(base) + 3], cn = kp[(base) + 23]; SLIDEJ(co, cn) } }

#define WINBODY(w) { \
    float M0 = sqrtf(fmaf(Wx0, Wx0, Wy0 * Wy0)); \
    float M1m = sqrtf(fmaf(Wx1, Wx1, Wy1 * Wy1)); \
    float M2m = sqrtf(fmaf(Wx2, Wx2, Wy2 * Wy2)); \
    float M3m = sqrtf(fmaf(Wx3, Wx3, Wy3 * Wy3)); \
    float lm = fmaxf(fmaxf(M0, M1m), fmaxf(M2m, v3 ? M3m : 0.f)); \
    lm = wavemax(lm); \
    if ((tid & 63) == 0) wred[tid >> 6] = lm; \
    __syncthreads(); \
    float bm = fmaxf(fmaxf(fmaxf(wred[0], wred[1]), fmaxf(wred[2], wred[3])), \
                     fmaxf(fmaxf(wred[4], wred[5]), fmaxf(wred[6], wred[7]))); \
    float cut = bm * alpha; \
    __syncthreads(); \
    if (w0 + (w) < NW) { \
        float r0v = 0.f, r1v = 0.f, r2v = 0.f, r3v = 0.f; \
        { float dr = Sv0.x - Wx0, di = Sv0.y - Wy0; float m1 = sqrtf(fmaf(dr, dr, di * di)); \
          if (M0 > cut) r0v = fminf(M0, m1 * M0); } \
        { float dr = Sv1.x - Wx1, di = Sv1.y - Wy1; float m1 = sqrtf(fmaf(dr, dr, di * di)); \
          if (M1m > cut) r1v = fminf(M1m, m1 * M1m); } \
        { float dr = Sv2.x - Wx2, di = Sv2.y - Wy2; float m1 = sqrtf(fmaf(dr, dr, di * di)); \
          if (M2m > cut) r2v = fminf(M2m, m1 * M2m); } \
        { float dr = Sv3.x - Wx3, di = Sv3.y - Wy3; float m1 = sqrtf(fmaf(dr, dr, di * di)); \
          if (M3m > cut) r3v = fminf(M3m, m1 * M3m); } \
        float* rp = resc + rbase + (size_t)(w) * RS; \
        rp[k0] = r0v; rp[k1] = r1v; rp[k2] = r2v; if (v3) rp[k3] = r3v; \
        rl = fmaxf(rl, fmaxf(fmaxf(r0v, r1v), fmaxf(r2v, r3v))); \
    } }

// K3: chunk of 8 consecutive windows per block; sliding-window spectrum
// update per bin; compact res + per-chunk max + per-batch atomic max.
__global__ __launch_bounds__(512, 4) void window_kernel(
        const float* __restrict__ ks, const float2* __restrict__ tw,
        const float2* __restrict__ S, const float* __restrict__ alpha_p,
        float* __restrict__ resc, float* __restrict__ cmax,
        unsigned int* __restrict__ rmax) {
    __shared__ float wred[8];
    int b = blockIdx.y;
    int wc = blockIdx.x;
    int w0 = wc * CW;
    int s0 = w0 * STEPW;
    int tid = threadIdx.x;
    float alpha = *alpha_p;
    const float* kp = ks + b * NP + s0;   // block-uniform -> s_load taps

    int k0 = tid, k1 = tid + 512, k2 = tid + 1024, k3 = tid + 1536;
    bool v3 = (k3 < KHALF);               // k3 <= 2047 < NP: loads always in-bounds

    float2 R0 = tw[k0], R1 = tw[k1], R2 = tw[k2], R3 = tw[k3];
    float2 T0 = tw[(20 * k0) % NP], T1 = tw[(20 * k1) % NP],
           T2 = tw[(20 * k2) % NP], T3 = tw[(20 * k3) % NP];
    float2 Q0 = tw[(k0 * s0) % NP], Q1 = tw[(k1 * s0) % NP],
           Q2 = tw[(k2 * s0) % NP], Q3 = tw[(k3 * s0) % NP];
    const float2* Sb = S + b * NP;
    float2 Sv0 = Sb[k0], Sv1 = Sb[k1], Sv2 = Sb[k2], Sv3 = Sb[k3];

    // Horner for first window: D = sum_j kp[j] r^j
    float Dx0 = kp[19], Dy0 = 0.f, Dx1 = kp[19], Dy1 = 0.f,
          Dx2 = kp[19], Dy2 = 0.f, Dx3 = kp[19], Dy3 = 0.f;
    #pragma unroll
    for (int j = 18; j >= 0; --j) {
        float a = kp[j];
        float nx, ny;
        nx = fmaf(Dx0, R0.x, fmaf(-Dy0, R0.y, a));
        ny = fmaf(Dy0, R0.x, Dx0 * R0.y);
        Dx0 = nx; Dy0 = ny;
        nx = fmaf(Dx1, R1.x, fmaf(-Dy1, R1.y, a));
        ny = fmaf(Dy1, R1.x, Dx1 * R1.y);
        Dx1 = nx; Dy1 = ny;
        nx = fmaf(Dx2, R2.x, fmaf(-Dy2, R2.y, a));
        ny = fmaf(Dy2, R2.x, Dx2 * R2.y);
        Dx2 = nx; Dy2 = ny;
        nx = fmaf(Dx3, R3.x, fmaf(-Dy3, R3.y, a));
        ny = fmaf(Dy3, R3.x, Dx3 * R3.y);
        Dx3 = nx; Dy3 = ny;
    }
    // absolute-phase spectrum W = Q * D
    float Wx0 = fmaf(Q0.x, Dx0, -(Q0.y * Dy0));
    float Wy0 = fmaf(Q0.x, Dy0, Q0.y * Dx0);
    float Wx1 = fmaf(Q1.x, Dx1, -(Q1.y * Dy1));
    float Wy1 = fmaf(Q1.x, Dy1, Q1.y * Dx1);
    float Wx2 = fmaf(Q2.x, Dx2, -(Q2.y * Dy2));
    float Wy2 = fmaf(Q2.x, Dy2, Q2.y * Dx2);
    float Wx3 = fmaf(Q3.x, Dx3, -(Q3.y * Dy3));
    float Wy3 = fmaf(Q3.x, Dy3, Q3.y * Dx3);

    float rl = 0.f;
    size_t rbase = (size_t)(b * NW + w0) * RS;

    WINBODY(0)
    SLIDE4(0)  WINBODY(1)
    SLIDE4(4)  WINBODY(2)
    SLIDE4(8)  WINBODY(3)
    SLIDE4(12) WINBODY(4)
    SLIDE4(16) WINBODY(5)
    SLIDE4(20) WINBODY(6)
    SLIDE4(24) WINBODY(7)

    rl = wavemax(rl);
    if ((tid & 63) == 0) wred[tid >> 6] = rl;
    __syncthreads();
    if (tid == 0) {
        float bm = fmaxf(fmaxf(fmaxf(wred[0], wred[1]), fmaxf(wred[2], wred[3])),
                         fmaxf(fmaxf(wred[4], wred[5]), fmaxf(wred[6], wred[7])));
        cmax[b * NCH + wc] = bm;
        atomicMax(&rmax[b], __float_as_uint(bm));
    }
}

// K4: out was memset to 0; write only survivors. Whole-chunk early-out.
__global__ __launch_bounds__(512) void sparse_kernel(
        const float* __restrict__ resc, const float* __restrict__ cmax,
        const unsigned int* __restrict__ rmax, const float* __restrict__ beta_p,
        float* __restrict__ out) {
    int b = blockIdx.y, w = blockIdx.x;
    float thr = (*beta_p) * __uint_as_float(rmax[b]);
    if (cmax[b * NCH + (w >> 3)] <= thr) return;
    const float* rp = resc + (size_t)(b * NW + w) * RS;
    size_t base = (size_t)(b * NW + w) * NP;
    int tid = threadIdx.x;
    #pragma unroll
    for (int c = 0; c < 4; ++c) {
        int k = tid + c * 512;
        if (k < KHALF) {
            float v = rp[k];
            if (v > thr) {
                out[base + k] = v;
                if (k > 0) out[base + NP - k] = v;
            }
        }
    }
}

extern "C" void kernel_launch(void* const* d_in, const int* in_sizes, int n_in,
                              void* d_out, int out_size, void* d_ws, size_t ws_size,
                              hipStream_t stream) {
    const float* sig       = (const float*)d_in[0];
    const float* alpha_p   = (const float*)d_in[1];
    const float* beta_p    = (const float*)d_in[2];
    const float* gamma_raw = (const float*)d_in[3];
    char* ws = (char*)d_ws;
    float*        ks   = (float*)(ws + 0);
    float2*       tw   = (float2*)(ws + 65536);
    float2*       S    = (float2*)(ws + 98304);
    unsigned int* rmax = (unsigned int*)(ws + 226304);
    float*        cmax = (float*)(ws + 226432);
    float*        resc = (float*)(ws + 262144);
    float* out = (float*)d_out;

    hipLaunchKernelGGL(init_kernel,   dim3(20),          dim3(256), 0, stream, sig, gamma_raw, ks, tw, rmax);
    hipLaunchKernelGGL(dft_kernel,    dim3(250, BATCH),  dim3(256), 0, stream, ks, S);
    hipLaunchKernelGGL(window_kernel, dim3(NCH, BATCH),  dim3(512), 0, stream, ks, tw, S, alpha_p, resc, cmax, rmax);
    hipMemsetAsync(d_out, 0, (size_t)out_size * sizeof(float), stream);
    hipLaunchKernelGGL(sparse_kernel, dim3(NW, BATCH),   dim3(512), 0, stream, resc, cmax, rmax, beta_p, out);
}

// Round 7
// 70.289 us; speedup vs baseline: 3.4407x; 1.0441x over previous
//
#include <hip/hip_runtime.h>
#include <math.h>

#define NSIG 1000
#define NP   3997      // interp points = FFT length (odd)
#define KHALF 1999     // distinct spectrum bins: k = 0..1998 (rest mirror)
#define NW   995       // n_windows
#define WIN  20
#define STEPW 4
#define BATCH 4
#define NCH  125       // window chunks per batch row (8 windows each)
#define CW   8         // windows per chunk
#define RS   2000      // compact res row stride (floats)

// ws layout (bytes), ws ~= 256 MiB:
//   ks   : [0, 65536)        BATCH*NP floats + pad
//   tw   : [65536, 97512)    NP float2
//   S    : [98304, 226208)   BATCH*NP float2 (first KHALF per row used)
//   rmax : [226304, 226320)  BATCH uint
//   cmax : [226432, 228432)  BATCH*NCH floats
//   resc : [262144, ~32MB)   BATCH*NW rows of RS floats (compact res)

__device__ __forceinline__ double interp_at(const float* __restrict__ s, int p) {
    int i0 = p >> 2;
    int si = p & 3;
    double ss = 0.25 * (double)si;
    const double A = -0.75;
    double d0 = ss + 1.0;
    double w0 = ((A * d0 - 5.0 * A) * d0 + 8.0 * A) * d0 - 4.0 * A;
    double w1 = ((A + 2.0) * ss - (A + 3.0)) * ss * ss + 1.0;
    double d2 = 1.0 - ss;
    double w2 = ((A + 2.0) * d2 - (A + 3.0)) * d2 * d2 + 1.0;
    double d3 = 2.0 - ss;
    double w3 = ((A * d3 - 5.0 * A) * d3 + 8.0 * A) * d3 - 4.0 * A;
    int im1 = i0 - 1; if (im1 < 0) im1 = 0;
    int ip1 = i0 + 1; if (ip1 > NSIG - 1) ip1 = NSIG - 1;
    int ip2 = i0 + 2; if (ip2 > NSIG - 1) ip2 = NSIG - 1;
    return w0 * (double)s[im1] + w1 * (double)s[i0] +
           w2 * (double)s[ip1] + w3 * (double)s[ip2];
}

// K1: blocks 0..15 twiddle table (+ block 0 zeroes rmax); 16..19 build ks.
__global__ __launch_bounds__(256) void init_kernel(
        const float* __restrict__ sig, const float* __restrict__ gamma_raw,
        float* __restrict__ ks, float2* __restrict__ tw,
        unsigned int* __restrict__ rmax) {
    int bx = blockIdx.x;
    int tid = threadIdx.x;
    if (bx < 16) {
        int m = bx * 256 + tid;
        if (m < NP) {
            double ang = -6.283185307179586476925286766559 * ((double)m / (double)NP);
            double sv, cv; sincos(ang, &sv, &cv);
            tw[m] = make_float2((float)cv, (float)sv);
        }
        if (bx == 0 && tid < BATCH) rmax[tid] = 0u;
        return;
    }
    __shared__ double red[256];
    int b = bx - 16;
    const float* srow = sig + b * NSIG;
    double lmin = 1e300;
    for (int p = tid; p < NP; p += 256)
        lmin = fmin(lmin, interp_at(srow, p));
    red[tid] = lmin;
    __syncthreads();
    for (int s = 128; s > 0; s >>= 1) {
        if (tid < s) red[tid] = fmin(red[tid], red[tid + s]);
        __syncthreads();
    }
    double m = fmin(red[0], 0.0);
    double g0r = (double)gamma_raw[0], g1r = (double)gamma_raw[1];
    double mx = fmax(g0r, g1r);
    double e0 = exp(g0r - mx), e1 = exp(g1r - mx);
    double inv = 1.0 / (e0 + e1);
    double g0 = e0 * inv, g1 = e1 * inv;
    for (int p = tid; p < NP; p += 256) {
        double x = interp_at(srow, p) - m;
        double poly = (x + 1.3) * (x + 1.3);
        double gauss = exp(-0.5 * (x - 0.7) * (x - 0.7));
        ks[b * NP + p] = (float)(g0 * poly + g1 * gauss);
    }
}

// K2: full DFT, half spectrum, double-precision phase recurrence.
__global__ __launch_bounds__(256) void dft_kernel(const float* __restrict__ ks,
                                                  float2* __restrict__ S) {
    __shared__ float  lks[NP];
    __shared__ double2 red[256];
    int b = blockIdx.y;
    int tid = threadIdx.x;
    int kk = tid & 7;
    int tc = tid >> 3;
    int k = blockIdx.x * 8 + kk;
    for (int i = tid; i < NP; i += 256) lks[i] = ks[b * NP + i];
    __syncthreads();

    double sr = 0.0, si = 0.0;
    if (k < KHALF) {
        int t0 = tc * 125;
        int t1 = t0 + 125; if (t1 > NP) t1 = NP;
        const double TWO_PI = 6.283185307179586476925286766559;
        double base = -TWO_PI / (double)NP;
        double rr, ri;
        sincos(base * (double)k, &ri, &rr);
        int m0 = (k * t0) % NP;
        double pr, pi;
        sincos(base * (double)m0, &pi, &pr);
        for (int t = t0; t < t1; ++t) {
            double kv = (double)lks[t];
            sr = fma(kv, pr, sr);
            si = fma(kv, pi, si);
            double nr = pr * rr - pi * ri;
            double ni = pr * ri + pi * rr;
            pr = nr; pi = ni;
        }
    }
    red[tid] = make_double2(sr, si);
    __syncthreads();
    for (int s = 128; s >= 8; s >>= 1) {
        if (tid < s) {
            red[tid].x += red[tid + s].x;
            red[tid].y += red[tid + s].y;
        }
        __syncthreads();
    }
    if (tid < 8) {
        int kw = blockIdx.x * 8 + tid;
        if (kw < KHALF)
            S[b * NP + kw] = make_float2((float)red[tid].x, (float)red[tid].y);
    }
}

__device__ __forceinline__ float wavemax(float x) {
    #pragma unroll
    for (int off = 32; off > 0; off >>= 1)
        x = fmaxf(x, __shfl_xor(x, off));
    return x;
}

// one sliding step for bin n with old tap co leaving, new tap cn entering:
// W += (cn*r20 - co) * q ; q *= r
#define SLIDE1(n, co, cn) { \
    float ax = fmaf((cn), T##n.x, -(co)); \
    float ay = (cn) * T##n.y; \
    Wx##n = fmaf(ax, Q##n.x, fmaf(-ay, Q##n.y, Wx##n)); \
    Wy##n = fmaf(ax, Q##n.y, fmaf(ay, Q##n.x, Wy##n)); \
    float tq = fmaf(Q##n.x, R##n.x, -(Q##n.y * R##n.y)); \
    Q##n.y = fmaf(Q##n.x, R##n.y, Q##n.y * R##n.x); \
    Q##n.x = tq; }

#define SLIDEJ(co, cn) SLIDE1(0, co, cn) SLIDE1(1, co, cn) SLIDE1(2, co, cn) SLIDE1(3, co, cn)

#define SLIDE4(base) { \
    { float co = kp[(base) + 0], cn = kp[(base) + 20]; SLIDEJ(co, cn) } \
    { float co = kp[(base) + 1], cn = kp[(base) + 21]; SLIDEJ(co, cn) } \
    { float co = kp[(base) + 2], cn = kp[(base) + 22]; SLIDEJ(co, cn) } \
    { float co = kp[(base) + 3], cn = kp[(base) + 23]; SLIDEJ(co, cn) } }

#define WINBODY(w) { \
    float M0 = sqrtf(fmaf(Wx0, Wx0, Wy0 * Wy0)); \
    float M1m = sqrtf(fmaf(Wx1, Wx1, Wy1 * Wy1)); \
    float M2m = sqrtf(fmaf(Wx2, Wx2, Wy2 * Wy2)); \
    float M3m = sqrtf(fmaf(Wx3, Wx3, Wy3 * Wy3)); \
    float lm = fmaxf(fmaxf(M0, M1m), fmaxf(M2m, v3 ? M3m : 0.f)); \
    lm = wavemax(lm); \
    if ((tid & 63) == 0) wred[tid >> 6] = lm; \
    __syncthreads(); \
    float bm = fmaxf(fmaxf(fmaxf(wred[0], wred[1]), fmaxf(wred[2], wred[3])), \
                     fmaxf(fmaxf(wred[4], wred[5]), fmaxf(wred[6], wred[7]))); \
    float cut = bm * alpha; \
    __syncthreads(); \
    if (w0 + (w) < NW) { \
        float r0v = 0.f, r1v = 0.f, r2v = 0.f, r3v = 0.f; \
        { float dr = Sv0.x - Wx0, di = Sv0.y - Wy0; float m1 = sqrtf(fmaf(dr, dr, di * di)); \
          if (M0 > cut) r0v = fminf(M0, m1 * M0); } \
        { float dr = Sv1.x - Wx1, di = Sv1.y - Wy1; float m1 = sqrtf(fmaf(dr, dr, di * di)); \
          if (M1m > cut) r1v = fminf(M1m, m1 * M1m); } \
        { float dr = Sv2.x - Wx2, di = Sv2.y - Wy2; float m1 = sqrtf(fmaf(dr, dr, di * di)); \
          if (M2m > cut) r2v = fminf(M2m, m1 * M2m); } \
        { float dr = Sv3.x - Wx3, di = Sv3.y - Wy3; float m1 = sqrtf(fmaf(dr, dr, di * di)); \
          if (M3m > cut) r3v = fminf(M3m, m1 * M3m); } \
        float* rp = resc + rbase + (size_t)(w) * RS; \
        rp[k0] = r0v; rp[k1] = r1v; rp[k2] = r2v; if (v3) rp[k3] = r3v; \
        rl = fmaxf(rl, fmaxf(fmaxf(r0v, r1v), fmaxf(r2v, r3v))); \
    } }

// K3: chunk of 8 consecutive windows per block; sliding-window spectrum
// update per bin; compact res + per-chunk max + per-batch atomic max.
__global__ __launch_bounds__(512, 4) void window_kernel(
        const float* __restrict__ ks, const float2* __restrict__ tw,
        const float2* __restrict__ S, const float* __restrict__ alpha_p,
        float* __restrict__ resc, float* __restrict__ cmax,
        unsigned int* __restrict__ rmax) {
    __shared__ float wred[8];
    int b = blockIdx.y;
    int wc = blockIdx.x;
    int w0 = wc * CW;
    int s0 = w0 * STEPW;
    int tid = threadIdx.x;
    float alpha = *alpha_p;
    const float* kp = ks + b * NP + s0;   // block-uniform -> s_load taps

    int k0 = tid, k1 = tid + 512, k2 = tid + 1024, k3 = tid + 1536;
    bool v3 = (k3 < KHALF);               // k3 <= 2047 < NP: loads always in-bounds

    float2 R0 = tw[k0], R1 = tw[k1], R2 = tw[k2], R3 = tw[k3];
    float2 T0 = tw[(20 * k0) % NP], T1 = tw[(20 * k1) % NP],
           T2 = tw[(20 * k2) % NP], T3 = tw[(20 * k3) % NP];
    float2 Q0 = tw[(k0 * s0) % NP], Q1 = tw[(k1 * s0) % NP],
           Q2 = tw[(k2 * s0) % NP], Q3 = tw[(k3 * s0) % NP];
    const float2* Sb = S + b * NP;
    float2 Sv0 = Sb[k0], Sv1 = Sb[k1], Sv2 = Sb[k2], Sv3 = Sb[k3];

    // Horner for first window: D = sum_j kp[j] r^j
    float Dx0 = kp[19], Dy0 = 0.f, Dx1 = kp[19], Dy1 = 0.f,
          Dx2 = kp[19], Dy2 = 0.f, Dx3 = kp[19], Dy3 = 0.f;
    #pragma unroll
    for (int j = 18; j >= 0; --j) {
        float a = kp[j];
        float nx, ny;
        nx = fmaf(Dx0, R0.x, fmaf(-Dy0, R0.y, a));
        ny = fmaf(Dy0, R0.x, Dx0 * R0.y);
        Dx0 = nx; Dy0 = ny;
        nx = fmaf(Dx1, R1.x, fmaf(-Dy1, R1.y, a));
        ny = fmaf(Dy1, R1.x, Dx1 * R1.y);
        Dx1 = nx; Dy1 = ny;
        nx = fmaf(Dx2, R2.x, fmaf(-Dy2, R2.y, a));
        ny = fmaf(Dy2, R2.x, Dx2 * R2.y);
        Dx2 = nx; Dy2 = ny;
        nx = fmaf(Dx3, R3.x, fmaf(-Dy3, R3.y, a));
        ny = fmaf(Dy3, R3.x, Dx3 * R3.y);
        Dx3 = nx; Dy3 = ny;
    }
    // absolute-phase spectrum W = Q * D
    float Wx0 = fmaf(Q0.x, Dx0, -(Q0.y * Dy0));
    float Wy0 = fmaf(Q0.x, Dy0, Q0.y * Dx0);
    float Wx1 = fmaf(Q1.x, Dx1, -(Q1.y * Dy1));
    float Wy1 = fmaf(Q1.x, Dy1, Q1.y * Dx1);
    float Wx2 = fmaf(Q2.x, Dx2, -(Q2.y * Dy2));
    float Wy2 = fmaf(Q2.x, Dy2, Q2.y * Dx2);
    float Wx3 = fmaf(Q3.x, Dx3, -(Q3.y * Dy3));
    float Wy3 = fmaf(Q3.x, Dy3, Q3.y * Dx3);

    float rl = 0.f;
    size_t rbase = (size_t)(b * NW + w0) * RS;

    WINBODY(0)
    SLIDE4(0)  WINBODY(1)
    SLIDE4(4)  WINBODY(2)
    SLIDE4(8)  WINBODY(3)
    SLIDE4(12) WINBODY(4)
    SLIDE4(16) WINBODY(5)
    SLIDE4(20) WINBODY(6)
    SLIDE4(24) WINBODY(7)

    rl = wavemax(rl);
    if ((tid & 63) == 0) wred[tid >> 6] = rl;
    __syncthreads();
    if (tid == 0) {
        float bm = fmaxf(fmaxf(fmaxf(wred[0], wred[1]), fmaxf(wred[2], wred[3])),
                         fmaxf(fmaxf(wred[4], wred[5]), fmaxf(wred[6], wred[7])));
        cmax[b * NCH + wc] = bm;
        atomicMax(&rmax[b], __float_as_uint(bm));
    }
}

// K4: finalize. One block per (b,w) row. Zero-rows written dense (no reads);
// surviving rows read compact resc, threshold, write full mirrored row.
// Every out element is written every call -> deterministic, no memset needed.
__global__ __launch_bounds__(1024) void finalize_kernel(
        const float* __restrict__ resc, const float* __restrict__ cmax,
        const unsigned int* __restrict__ rmax, const float* __restrict__ beta_p,
        float* __restrict__ out) {
    int b = blockIdx.y, w = blockIdx.x;
    float thr = (*beta_p) * __uint_as_float(rmax[b]);
    size_t base = (size_t)(b * NW + w) * NP;
    int tid = threadIdx.x;
    if (cmax[b * NCH + (w >> 3)] <= thr) {
        // all-zero row: coalesced dense zero fill
        #pragma unroll
        for (int c = 0; c < 4; ++c) {
            int i = tid + c * 1024;
            if (i < NP) out[base + i] = 0.f;
        }
        return;
    }
    const float* rp = resc + (size_t)(b * NW + w) * RS;
    #pragma unroll
    for (int c = 0; c < 2; ++c) {
        int k = tid + c * 1024;
        if (k < KHALF) {
            float v = rp[k];
            float f = (v > thr) ? v : 0.f;
            out[base + k] = f;
            if (k > 0) out[base + NP - k] = f;
        }
    }
}

extern "C" void kernel_launch(void* const* d_in, const int* in_sizes, int n_in,
                              void* d_out, int out_size, void* d_ws, size_t ws_size,
                              hipStream_t stream) {
    const float* sig       = (const float*)d_in[0];
    const float* alpha_p   = (const float*)d_in[1];
    const float* beta_p    = (const float*)d_in[2];
    const float* gamma_raw = (const float*)d_in[3];
    char* ws = (char*)d_ws;
    float*        ks   = (float*)(ws + 0);
    float2*       tw   = (float2*)(ws + 65536);
    float2*       S    = (float2*)(ws + 98304);
    unsigned int* rmax = (unsigned int*)(ws + 226304);
    float*        cmax = (float*)(ws + 226432);
    float*        resc = (float*)(ws + 262144);
    float* out = (float*)d_out;

    hipLaunchKernelGGL(init_kernel,     dim3(20),         dim3(256),  0, stream, sig, gamma_raw, ks, tw, rmax);
    hipLaunchKernelGGL(dft_kernel,      dim3(250, BATCH), dim3(256),  0, stream, ks, S);
    hipLaunchKernelGGL(window_kernel,   dim3(NCH, BATCH), dim3(512),  0, stream, ks, tw, S, alpha_p, resc, cmax, rmax);
    hipLaunchKernelGGL(finalize_kernel, dim3(NW, BATCH),  dim3(1024), 0, stream, resc, cmax, rmax, beta_p, out);
}